// Round 2
// baseline (485.034 us; speedup 1.0000x reference)
//
#include <hip/hip_runtime.h>

#define N 8192
#define F 128
#define ALPHA 0.2f

typedef __attribute__((ext_vector_type(8))) short short8;
typedef __attribute__((ext_vector_type(4))) float f32x4;
typedef unsigned short u16;

__device__ __forceinline__ u16 f2bf(float f) {
    unsigned int u = __float_as_uint(f);
    u += 0x7fff + ((u >> 16) & 1);  // RNE; inputs are finite, no NaN handling needed
    return (u16)(u >> 16);
}

// ---------------- K1: h = x@W ; emit hT (bf16, [feature][node]) + ssrc/sdst (fp32) ----------------
__global__ __launch_bounds__(256) void gemm_h(const float* __restrict__ x,
                                              const float* __restrict__ W,
                                              const float* __restrict__ aa,
                                              u16* __restrict__ hT,
                                              float* __restrict__ ssrc,
                                              float* __restrict__ sdst) {
    __shared__ float xs[32 * 128];
    __shared__ float Wsh[32 * 128];
    const int t = threadIdx.x;
    const int i0 = blockIdx.x * 32;
    const int c4 = (t & 31) * 4;
    const int r8 = t >> 5;

#pragma unroll
    for (int p = 0; p < 4; ++p) {
        int rr = p * 8 + r8;
        *(float4*)&xs[rr * 128 + c4] = *(const float4*)&x[(size_t)(i0 + rr) * 128 + c4];
    }

    const int tx = t & 31, ty = t >> 5;
    const int r0 = ty * 4, c0 = tx * 4;
    float acc[4][4] = {};

    for (int kc = 0; kc < 4; ++kc) {
        __syncthreads();
#pragma unroll
        for (int p = 0; p < 4; ++p) {
            int k = p * 8 + r8;
            *(float4*)&Wsh[k * 128 + c4] = *(const float4*)&W[(kc * 32 + k) * 128 + c4];
        }
        __syncthreads();
#pragma unroll 4
        for (int k = 0; k < 32; k += 4) {
            float xr[4][4];
#pragma unroll
            for (int rr = 0; rr < 4; ++rr)
                *(float4*)xr[rr] = *(const float4*)&xs[(r0 + rr) * 128 + kc * 32 + k];
#pragma unroll
            for (int kk = 0; kk < 4; ++kk) {
                float4 wv = *(const float4*)&Wsh[(k + kk) * 128 + c0];
#pragma unroll
                for (int rr = 0; rr < 4; ++rr) {
                    acc[rr][0] += xr[rr][kk] * wv.x;
                    acc[rr][1] += xr[rr][kk] * wv.y;
                    acc[rr][2] += xr[rr][kk] * wv.z;
                    acc[rr][3] += xr[rr][kk] * wv.w;
                }
            }
        }
    }

    // epilogue 1: hT bf16 transposed store
#pragma unroll
    for (int rr = 0; rr < 4; ++rr)
#pragma unroll
        for (int cc = 0; cc < 4; ++cc)
            hT[(size_t)(c0 + cc) * N + (i0 + r0 + rr)] = f2bf(acc[rr][cc]);

    // epilogue 2: fused scores s_src/s_dst from full-precision accumulators
    float4 asv = *(const float4*)&aa[c0];
    float4 adv = *(const float4*)&aa[F + c0];
#pragma unroll
    for (int rr = 0; rr < 4; ++rr) {
        float vs = acc[rr][0] * asv.x + acc[rr][1] * asv.y + acc[rr][2] * asv.z + acc[rr][3] * asv.w;
        float vd = acc[rr][0] * adv.x + acc[rr][1] * adv.y + acc[rr][2] * adv.z + acc[rr][3] * adv.w;
#pragma unroll
        for (int off = 16; off >= 1; off >>= 1) {
            vs += __shfl_down(vs, off, 32);
            vd += __shfl_down(vd, off, 32);
        }
        if (tx == 0) {
            ssrc[i0 + r0 + rr] = vs;
            sdst[i0 + r0 + rr] = vd;
        }
    }
}

// ---------------- K2: fused attention, barrier-free main loop ----------------
// Block = 4 independent waves over the SAME 16 i-rows. Wave w owns j-quarter
// [w*2048, (w+1)*2048) and ALL 128 feature cols. The 16x16x32 A-frag (lane: row=l&15,
// k=quad*8+e) is produced in-register by the owning wave -> no LDS sharing, no
// main-loop __syncthreads. adj: depth-3 register pipeline (~3 iters issue-to-use).
// Epilogue: one barrier, LDS-reduce 4 quarter-accs + row sums, write normalized out.
__global__ __launch_bounds__(256, 2) void attn_fused(const int* __restrict__ adj,
                                                     const u16* __restrict__ hT,
                                                     const float* __restrict__ ssrc,
                                                     const float* __restrict__ sdst,
                                                     float* __restrict__ out) {
    __shared__ float accsh[4][16][132];  // 33.8 KB, col-padded 128->132 (banks)
    __shared__ float srow[4][16];

    const int t = threadIdx.x;
    const int w = t >> 6, L = t & 63;
    const int quad = L >> 4, l16 = L & 15;
    const int tile0 = blockIdx.x * 16;     // grid.x = N/16 = 512
    const int prow = tile0 + l16;
    const int JW = N / 4;                  // 2048 cols per wave
    const int jbase = w * JW;
    const int NC = JW / 32;                // 64 chunks of 32 j

    const float s_i = ssrc[prow];
    const int* pA = adj + (size_t)prow * N + jbase + quad * 8;
    const float* pD = sdst + jbase + quad * 8;
    const u16* pB = hT + (size_t)l16 * N + jbase + quad * 8;

    f32x4 acc[8];
#pragma unroll
    for (int cg = 0; cg < 8; ++cg) acc[cg] = 0.f;
    float rsum = 0.f;

    // 8 w values -> bf16 A-frag in-register (v_cvt_pk_bf16_f32 RNE == f2bf) + exact bf16 rowsum
    auto mk_frag = [&](int4 a0, int4 a1, float4 d0, float4 d1) -> short8 {
        const int m[8] = {a0.x, a0.y, a0.z, a0.w, a1.x, a1.y, a1.z, a1.w};
        const float d[8] = {d0.x, d0.y, d0.z, d0.w, d1.x, d1.y, d1.z, d1.w};
        float wv[8];
#pragma unroll
        for (int k = 0; k < 8; ++k) {
            float z = s_i + d[k];
            float e = __expf(fmaxf(z, ALPHA * z));
            wv[k] = (m[k] > 0) ? e : 0.f;
        }
        union { unsigned int u[4]; short8 s8; } pk;
        float s = 0.f;
#pragma unroll
        for (int p = 0; p < 4; ++p) {
            unsigned int r;
            asm("v_cvt_pk_bf16_f32 %0, %1, %2" : "=v"(r) : "v"(wv[2 * p]), "v"(wv[2 * p + 1]));
            pk.u[p] = r;
            s += __uint_as_float(r << 16);
            s += __uint_as_float(r & 0xffff0000u);
        }
        rsum += s;
        return pk.s8;
    };

    // ---- prologue: adj chunks 0,1,2 in flight; sdst chunk 0 ----
    int4 aA0 = *(const int4*)(pA);
    int4 aA1 = *(const int4*)(pA + 4);
    int4 aB0 = *(const int4*)(pA + 32);
    int4 aB1 = *(const int4*)(pA + 36);
    int4 aC0 = *(const int4*)(pA + 64);
    int4 aC1 = *(const int4*)(pA + 68);
    float4 dA0 = *(const float4*)(pD);
    float4 dA1 = *(const float4*)(pD + 4);

    for (int c = 0; c < NC; ++c) {
        const int coff = c * 32;

        // prefetch: adj chunk c+3 (depth-3, HBM), sdst chunk c+1 (depth-1, L2)
        const int ca = (c + 3 < NC) ? c + 3 : NC - 1;
        const int cd = (c + 1 < NC) ? c + 1 : NC - 1;
        int4 nA0 = *(const int4*)(pA + ca * 32);
        int4 nA1 = *(const int4*)(pA + ca * 32 + 4);
        float4 nD0 = *(const float4*)(pD + cd * 32);
        float4 nD1 = *(const float4*)(pD + cd * 32 + 4);

        // B-frags for this chunk (L2-resident hT); latency covered by mk_frag VALU below
        short8 Bv[8];
#pragma unroll
        for (int cg = 0; cg < 8; ++cg)
            Bv[cg] = *(const short8*)(pB + (size_t)cg * 16 * N + coff);

        // A-frag from adj regs issued 3 iterations ago
        short8 af = mk_frag(aA0, aA1, dA0, dA1);

#pragma unroll
        for (int cg = 0; cg < 8; ++cg)
            acc[cg] = __builtin_amdgcn_mfma_f32_16x16x32_bf16(af, Bv[cg], acc[cg], 0, 0, 0);

        // rotate pipelines
        aA0 = aB0; aA1 = aB1;
        aB0 = aC0; aB1 = aC1;
        aC0 = nA0; aC1 = nA1;
        dA0 = nD0; dA1 = nD1;
    }

    // ---- epilogue: combine 4 j-quarters in LDS, normalize, store ----
    rsum += __shfl_xor(rsum, 16);
    rsum += __shfl_xor(rsum, 32);   // all quads now hold row-sum for row l16 (this quarter)
    if (L < 16) srow[w][l16] = rsum;

    // D layout: col = l&15, row = quad*4 + reg
#pragma unroll
    for (int cg = 0; cg < 8; ++cg)
#pragma unroll
        for (int r = 0; r < 4; ++r)
            accsh[w][quad * 4 + r][cg * 16 + l16] = acc[cg][r];

    __syncthreads();

#pragma unroll
    for (int p = 0; p < 2; ++p) {
        const int fid = t * 2 + p;          // 0..511 -> 16 rows x 32 float4-cols
        const int row = fid >> 5;
        const int c4 = (fid & 31) * 4;
        float4 s0 = *(const float4*)&accsh[0][row][c4];
        float4 s1 = *(const float4*)&accsh[1][row][c4];
        float4 s2 = *(const float4*)&accsh[2][row][c4];
        float4 s3 = *(const float4*)&accsh[3][row][c4];
        const float inv = 1.0f / (srow[0][row] + srow[1][row] + srow[2][row] + srow[3][row]);
        float4 o = {(s0.x + s1.x + s2.x + s3.x) * inv,
                    (s0.y + s1.y + s2.y + s3.y) * inv,
                    (s0.z + s1.z + s2.z + s3.z) * inv,
                    (s0.w + s1.w + s2.w + s3.w) * inv};
        *(float4*)&out[(size_t)(tile0 + row) * F + c4] = o;
    }
}

extern "C" void kernel_launch(void* const* d_in, const int* in_sizes, int n_in,
                              void* d_out, int out_size, void* d_ws, size_t ws_size,
                              hipStream_t stream) {
    (void)in_sizes; (void)n_in; (void)out_size; (void)ws_size;
    const float* x   = (const float*)d_in[0];
    const int*   adj = (const int*)d_in[1];
    const float* W   = (const float*)d_in[2];
    const float* a   = (const float*)d_in[3];
    float* out = (float*)d_out;

    u16* hT     = (u16*)d_ws;                    // N*F bf16 (2 MB)
    float* ssrc = (float*)(hT + (size_t)N * F);  // N
    float* sdst = ssrc + N;                      // N

    gemm_h<<<N / 32, 256, 0, stream>>>(x, W, a, hT, ssrc, sdst);
    attn_fused<<<N / 16, 256, 0, stream>>>(adj, hT, ssrc, sdst, out);
}

// Round 3
// 484.716 us; speedup vs baseline: 1.0007x; 1.0007x over previous
//
#include <hip/hip_runtime.h>

#define N 8192
#define F 128
#define ALPHA 0.2f

typedef __attribute__((ext_vector_type(8))) short short8;
typedef __attribute__((ext_vector_type(4))) float f32x4;
typedef unsigned short u16;

__device__ __forceinline__ u16 f2bf(float f) {
    unsigned int u = __float_as_uint(f);
    u += 0x7fff + ((u >> 16) & 1);  // RNE; inputs are finite, no NaN handling needed
    return (u16)(u >> 16);
}

// ---------------- K1: h = x@W ; emit hT (bf16, [feature][node]) + ssrc/sdst (fp32) ----------------
__global__ __launch_bounds__(256) void gemm_h(const float* __restrict__ x,
                                              const float* __restrict__ W,
                                              const float* __restrict__ aa,
                                              u16* __restrict__ hT,
                                              float* __restrict__ ssrc,
                                              float* __restrict__ sdst) {
    __shared__ float xs[32 * 128];
    __shared__ float Wsh[32 * 128];
    const int t = threadIdx.x;
    const int i0 = blockIdx.x * 32;
    const int c4 = (t & 31) * 4;
    const int r8 = t >> 5;

#pragma unroll
    for (int p = 0; p < 4; ++p) {
        int rr = p * 8 + r8;
        *(float4*)&xs[rr * 128 + c4] = *(const float4*)&x[(size_t)(i0 + rr) * 128 + c4];
    }

    const int tx = t & 31, ty = t >> 5;
    const int r0 = ty * 4, c0 = tx * 4;
    float acc[4][4] = {};

    for (int kc = 0; kc < 4; ++kc) {
        __syncthreads();
#pragma unroll
        for (int p = 0; p < 4; ++p) {
            int k = p * 8 + r8;
            *(float4*)&Wsh[k * 128 + c4] = *(const float4*)&W[(kc * 32 + k) * 128 + c4];
        }
        __syncthreads();
#pragma unroll 4
        for (int k = 0; k < 32; k += 4) {
            float xr[4][4];
#pragma unroll
            for (int rr = 0; rr < 4; ++rr)
                *(float4*)xr[rr] = *(const float4*)&xs[(r0 + rr) * 128 + kc * 32 + k];
#pragma unroll
            for (int kk = 0; kk < 4; ++kk) {
                float4 wv = *(const float4*)&Wsh[(k + kk) * 128 + c0];
#pragma unroll
                for (int rr = 0; rr < 4; ++rr) {
                    acc[rr][0] += xr[rr][kk] * wv.x;
                    acc[rr][1] += xr[rr][kk] * wv.y;
                    acc[rr][2] += xr[rr][kk] * wv.z;
                    acc[rr][3] += xr[rr][kk] * wv.w;
                }
            }
        }
    }

    // epilogue 1: hT bf16 transposed store
#pragma unroll
    for (int rr = 0; rr < 4; ++rr)
#pragma unroll
        for (int cc = 0; cc < 4; ++cc)
            hT[(size_t)(c0 + cc) * N + (i0 + r0 + rr)] = f2bf(acc[rr][cc]);

    // epilogue 2: fused scores s_src/s_dst from full-precision accumulators
    float4 asv = *(const float4*)&aa[c0];
    float4 adv = *(const float4*)&aa[F + c0];
#pragma unroll
    for (int rr = 0; rr < 4; ++rr) {
        float vs = acc[rr][0] * asv.x + acc[rr][1] * asv.y + acc[rr][2] * asv.z + acc[rr][3] * asv.w;
        float vd = acc[rr][0] * adv.x + acc[rr][1] * adv.y + acc[rr][2] * adv.z + acc[rr][3] * adv.w;
#pragma unroll
        for (int off = 16; off >= 1; off >>= 1) {
            vs += __shfl_down(vs, off, 32);
            vd += __shfl_down(vd, off, 32);
        }
        if (tx == 0) {
            ssrc[i0 + r0 + rr] = vs;
            sdst[i0 + r0 + rr] = vd;
        }
    }
}

// ---------------- K2: fused attention, barrier-free main loop ----------------
// Block = 4 independent waves over the SAME 16 i-rows; wave w owns j-quarter
// [w*2048,(w+1)*2048) and all 128 features. Register pipelines, ISSUE ORDER MATTERS
// (vmcnt retires in order): per iter we issue B(c+1) FIRST, then adj(c+4)/sdst(c+2),
// then mk_frag(c) [regs 4 iters old], then MFMA(c) on Bbuf loaded LAST iteration.
// So the MFMA's waitcnt is vmcnt(~16) (trivially satisfied), never a drain behind
// the in-flight HBM adj prefetch. One barrier total (epilogue reduce+normalize).
__global__ __launch_bounds__(256, 2) void attn_fused(const int* __restrict__ adj,
                                                     const u16* __restrict__ hT,
                                                     const float* __restrict__ ssrc,
                                                     const float* __restrict__ sdst,
                                                     float* __restrict__ out) {
    __shared__ float accsh[4][16][132];  // 33.8 KB, col-padded 128->132
    __shared__ float srow[4][16];

    const int t = threadIdx.x;
    const int w = t >> 6, L = t & 63;
    const int quad = L >> 4, l16 = L & 15;
    const int tile0 = blockIdx.x * 16;     // grid.x = N/16 = 512
    const int prow = tile0 + l16;
    const int JW = N / 4;                  // 2048 cols per wave
    const int jbase = w * JW;
    const int NC = JW / 32;                // 64 chunks of 32 j

    const float s_i = ssrc[prow];
    const int* pA = adj + (size_t)prow * N + jbase + quad * 8;
    const float* pD = sdst + jbase + quad * 8;
    const u16* pB = hT + (size_t)l16 * N + jbase + quad * 8;

    f32x4 acc[8];
#pragma unroll
    for (int cg = 0; cg < 8; ++cg) acc[cg] = 0.f;
    float rsum = 0.f;

    // 8 w values -> bf16 A-frag in-register (v_cvt_pk_bf16_f32 RNE == f2bf) + exact bf16 rowsum
    auto mk_frag = [&](int4 a0, int4 a1, float4 d0, float4 d1) -> short8 {
        const int m[8] = {a0.x, a0.y, a0.z, a0.w, a1.x, a1.y, a1.z, a1.w};
        const float d[8] = {d0.x, d0.y, d0.z, d0.w, d1.x, d1.y, d1.z, d1.w};
        float wv[8];
#pragma unroll
        for (int k = 0; k < 8; ++k) {
            float z = s_i + d[k];
            float e = __expf(fmaxf(z, ALPHA * z));
            wv[k] = (m[k] > 0) ? e : 0.f;
        }
        union { unsigned int u[4]; short8 s8; } pk;
        float s = 0.f;
#pragma unroll
        for (int p = 0; p < 4; ++p) {
            unsigned int r;
            asm("v_cvt_pk_bf16_f32 %0, %1, %2" : "=v"(r) : "v"(wv[2 * p]), "v"(wv[2 * p + 1]));
            pk.u[p] = r;
            s += __uint_as_float(r << 16);
            s += __uint_as_float(r & 0xffff0000u);
        }
        rsum += s;
        return pk.s8;
    };

    // ---- prologue ----
    // adj pipeline depth 4 (chunks 0..3), sdst depth 2 (chunks 0,1), B chunk 0
    int4 A0x = *(const int4*)(pA);       int4 A0y = *(const int4*)(pA + 4);
    int4 A1x = *(const int4*)(pA + 32);  int4 A1y = *(const int4*)(pA + 36);
    int4 A2x = *(const int4*)(pA + 64);  int4 A2y = *(const int4*)(pA + 68);
    int4 A3x = *(const int4*)(pA + 96);  int4 A3y = *(const int4*)(pA + 100);
    float4 D0x = *(const float4*)(pD);      float4 D0y = *(const float4*)(pD + 4);
    float4 D1x = *(const float4*)(pD + 32); float4 D1y = *(const float4*)(pD + 36);

    short8 Bbuf[8];
#pragma unroll
    for (int cg = 0; cg < 8; ++cg)
        Bbuf[cg] = *(const short8*)(pB + (size_t)cg * 16 * N);

    for (int c = 0; c < NC; ++c) {
        // 1. B(c+1) — issued now, consumed NEXT iteration (clamped tail reload: harmless)
        const int cb = (c + 1 < NC) ? c + 1 : NC - 1;
        short8 Bload[8];
#pragma unroll
        for (int cg = 0; cg < 8; ++cg)
            Bload[cg] = *(const short8*)(pB + (size_t)cg * 16 * N + cb * 32);

        // 2. adj(c+4) [HBM, depth-4], sdst(c+2) [L2, depth-2]
        const int ca = (c + 4 < NC) ? c + 4 : NC - 1;
        const int cd = (c + 2 < NC) ? c + 2 : NC - 1;
        int4 nAx = *(const int4*)(pA + ca * 32);
        int4 nAy = *(const int4*)(pA + ca * 32 + 4);
        float4 nDx = *(const float4*)(pD + cd * 32);
        float4 nDy = *(const float4*)(pD + cd * 32 + 4);

        // 3. A-frag for chunk c from regs issued 4 iterations ago
        short8 af = mk_frag(A0x, A0y, D0x, D0y);

        // 4. MFMA chunk c on B regs loaded last iteration
#pragma unroll
        for (int cg = 0; cg < 8; ++cg)
            acc[cg] = __builtin_amdgcn_mfma_f32_16x16x32_bf16(af, Bbuf[cg], acc[cg], 0, 0, 0);

        // 5. rotate pipelines
        A0x = A1x; A0y = A1y;
        A1x = A2x; A1y = A2y;
        A2x = A3x; A2y = A3y;
        A3x = nAx; A3y = nAy;
        D0x = D1x; D0y = D1y;
        D1x = nDx; D1y = nDy;
#pragma unroll
        for (int cg = 0; cg < 8; ++cg) Bbuf[cg] = Bload[cg];
    }

    // ---- epilogue: combine 4 j-quarters in LDS, normalize, store ----
    rsum += __shfl_xor(rsum, 16);
    rsum += __shfl_xor(rsum, 32);   // all quads hold this quarter's row-sum for row l16
    if (L < 16) srow[w][l16] = rsum;

    // D layout: col = l&15, row = quad*4 + reg
#pragma unroll
    for (int cg = 0; cg < 8; ++cg)
#pragma unroll
        for (int r = 0; r < 4; ++r)
            accsh[w][quad * 4 + r][cg * 16 + l16] = acc[cg][r];

    __syncthreads();

#pragma unroll
    for (int p = 0; p < 2; ++p) {
        const int fid = t * 2 + p;          // 0..511 -> 16 rows x 32 float4-cols
        const int row = fid >> 5;
        const int c4 = (fid & 31) * 4;
        float4 s0 = *(const float4*)&accsh[0][row][c4];
        float4 s1 = *(const float4*)&accsh[1][row][c4];
        float4 s2 = *(const float4*)&accsh[2][row][c4];
        float4 s3 = *(const float4*)&accsh[3][row][c4];
        const float inv = 1.0f / (srow[0][row] + srow[1][row] + srow[2][row] + srow[3][row]);
        float4 o = {(s0.x + s1.x + s2.x + s3.x) * inv,
                    (s0.y + s1.y + s2.y + s3.y) * inv,
                    (s0.z + s1.z + s2.z + s3.z) * inv,
                    (s0.w + s1.w + s2.w + s3.w) * inv};
        *(float4*)&out[(size_t)(tile0 + row) * F + c4] = o;
    }
}

extern "C" void kernel_launch(void* const* d_in, const int* in_sizes, int n_in,
                              void* d_out, int out_size, void* d_ws, size_t ws_size,
                              hipStream_t stream) {
    (void)in_sizes; (void)n_in; (void)out_size; (void)ws_size;
    const float* x   = (const float*)d_in[0];
    const int*   adj = (const int*)d_in[1];
    const float* W   = (const float*)d_in[2];
    const float* a   = (const float*)d_in[3];
    float* out = (float*)d_out;

    u16* hT     = (u16*)d_ws;                    // N*F bf16 (2 MB)
    float* ssrc = (float*)(hT + (size_t)N * F);  // N
    float* sdst = ssrc + N;                      // N

    gemm_h<<<N / 32, 256, 0, stream>>>(x, W, a, hT, ssrc, sdst);
    attn_fused<<<N / 16, 256, 0, stream>>>(adj, hT, ssrc, sdst, out);
}